// Round 10
// baseline (111.925 us; speedup 1.0000x reference)
//
#include <hip/hip_runtime.h>
#include <math.h>

#define NB 4
#define CH 256
#define NHEADS 4
#define HC 64
#define NT 2304    // 48*48
#define KSEG 1152  // keys per segment (split-K x2)
#define NSEG 18    // 64-key chunks per segment

typedef _Float16 f16;
typedef _Float16 f16x4 __attribute__((ext_vector_type(4)));
typedef _Float16 f16x8 __attribute__((ext_vector_type(8)));
typedef float f32x4 __attribute__((ext_vector_type(4)));
typedef float f32x16 __attribute__((ext_vector_type(16)));

#define MFMA16(a, b, c) __builtin_amdgcn_mfma_f32_16x16x32_f16(a, b, c, 0, 0, 0)
#define MFMA32(a, b, c) __builtin_amdgcn_mfma_f32_32x32x16_f16(a, b, c, 0, 0, 0)
#define SBAR() __builtin_amdgcn_sched_barrier(0)

__device__ __forceinline__ void gload_lds16(const void* g, void* l) {
    __builtin_amdgcn_global_load_lds(
        (const __attribute__((address_space(1))) unsigned int*)g,
        (__attribute__((address_space(3))) unsigned int*)l, 16, 0, 0);
}

__device__ __forceinline__ unsigned pkh(float a, float b) {
    auto r = __builtin_amdgcn_cvt_pkrtz(a, b);   // __fp16 ext_vector(2)
    return __builtin_bit_cast(unsigned, r);
}
// v_permlane32_swap_b32: new_a = [a.lo32 | b.lo32_old], new_b = [a.hi32_old | b.hi32]
__device__ __forceinline__ void swap32(unsigned& a, unsigned& b) {
    asm volatile("v_permlane32_swap_b32 %0, %1" : "+v"(a), "+v"(b));
}

// ---------------------------------------------------------------------------
// Fused K/Q/V projection reading x directly (unchanged from R9).
// grid (36, 3, 4), block 256. Outputs: K,Q [b][h][n][64c]; V [b][h][64c][n].
// ---------------------------------------------------------------------------
__global__ __launch_bounds__(256) void proj_qkv_mfma(
    const float* __restrict__ wk, const float* __restrict__ bk,
    const float* __restrict__ wq, const float* __restrict__ bq,
    const float* __restrict__ wv, const float* __restrict__ bv,
    const float* __restrict__ X,
    f16* __restrict__ Kt, f16* __restrict__ Qt, f16* __restrict__ Vg)
{
    const int t = threadIdx.x, l = t & 63, w = t >> 6;
    const int lm = l & 15, lg = l >> 4;
    const int n0 = blockIdx.x * 64;
    const int sel = blockIdx.y;
    const int b = blockIdx.z;

    const float* W  = sel == 0 ? wk : (sel == 1 ? wq : wv);
    const float* Bi = sel == 0 ? bk : (sel == 1 ? bq : bv);

    f32x4 acc[4][4] = {};   // [h][nt]

#pragma unroll 2
    for (int ks = 0; ks < 8; ++ks) {
        f16x8 bf[4];
#pragma unroll
        for (int nt = 0; nt < 4; ++nt) {
            const float* xp = &X[((size_t)b * CH + ks * 32 + lg * 8) * NT
                                 + n0 + nt * 16 + lm];
            f16x8 v;
#pragma unroll
            for (int j = 0; j < 8; ++j) v[j] = (f16)xp[(size_t)j * NT];
            bf[nt] = v;
        }
#pragma unroll
        for (int h = 0; h < 4; ++h) {
            const float* wp = &W[(size_t)(h * 64 + w * 16 + lm) * CH + ks * 32 + lg * 8];
            const float4 wa = *reinterpret_cast<const float4*>(wp);
            const float4 wb = *reinterpret_cast<const float4*>(wp + 4);
            const f16x8 a = {(f16)wa.x, (f16)wa.y, (f16)wa.z, (f16)wa.w,
                             (f16)wb.x, (f16)wb.y, (f16)wb.z, (f16)wb.w};
#pragma unroll
            for (int nt = 0; nt < 4; ++nt)
                acc[h][nt] = MFMA16(a, bf[nt], acc[h][nt]);
        }
    }

    const int c_base = w * 16 + lg * 4;
#pragma unroll
    for (int h = 0; h < 4; ++h) {
        const float4 b4 = *reinterpret_cast<const float4*>(&Bi[h * 64 + c_base]);
        const float bb[4] = {b4.x, b4.y, b4.z, b4.w};
        if (sel < 2) {
            f16* Out = sel == 0 ? Kt : Qt;
#pragma unroll
            for (int nt = 0; nt < 4; ++nt) {
                const int n = n0 + nt * 16 + lm;
                f16x4 o = {(f16)(acc[h][nt][0] + bb[0]), (f16)(acc[h][nt][1] + bb[1]),
                           (f16)(acc[h][nt][2] + bb[2]), (f16)(acc[h][nt][3] + bb[3])};
                *reinterpret_cast<f16x4*>(
                    &Out[((size_t)((b * NHEADS + h) * NT + n)) * HC + c_base]) = o;
            }
        } else {
#pragma unroll
            for (int nt = 0; nt < 4; ++nt) {
                const int n = n0 + nt * 16 + lm;
#pragma unroll
                for (int r = 0; r < 4; ++r)
                    Vg[((size_t)((b * NHEADS + h) * HC + c_base + r)) * NT + n] =
                        (f16)(acc[h][nt][r] + bb[r]);
            }
        }
    }
}

// ---------------------------------------------------------------------------
// Flash attention, 32x32x16 MFMA, split-K x2, COUNTED-VMCNT PIPELINE (T4).
// Double-buffered K/V (64KB LDS). Per chunk: each wave waits only its OWN 8
// staging loads (s_waitcnt vmcnt(8)) + raw s_barrier -> the next chunk's
// prefetch stays in flight across barriers (never vmcnt(0) in the loop).
// sched_barrier(0) pins ordering around each wait/barrier (guide rule #18).
// s_setprio(1) around MFMA clusters (T5). Rest as R9: swizzled gload_lds
// staging, in-register P, defer-max THR=8, exact f32 segment merge.
// grid 576, block 256.
// ---------------------------------------------------------------------------
__global__ __launch_bounds__(256) void attn_pipe(
    const f16* __restrict__ Kt, const f16* __restrict__ Qt,
    const f16* __restrict__ Vg, f16* __restrict__ Ot)
{
    __shared__ f16 SM[2][2][2][4096];   // [buf][seg][K/V][64 rows x 64c]
    __shared__ float Ml[2][64], Ll[2][64];

    const int t = threadIdx.x, l = t & 63, w = t >> 6;
    const int col = l & 31, hi = l >> 5;
    const int qh = w & 1, sg = w >> 1;   // query half, key segment

    const int bid = blockIdx.x;
    const int xcd = bid & 7, idx = bid >> 3;
    const int bh  = 2 * xcd + (idx >= 36 ? 1 : 0);
    const int qt  = idx >= 36 ? idx - 36 : idx;
    const int b = bh >> 2, h = bh & 3;
    const int m0 = qt * 64;

    const size_t bhs = (size_t)(b * NHEADS + h);
    const f16* Kb = Kt + bhs * NT * HC;   // [n][64c] rows of 128 B
    const f16* Qb = Qt + bhs * NT * HC;
    const f16* Vb = Vg + bhs * HC * NT;   // [c][n]

    const int srow = l >> 3, su = l & 7, sx = su ^ srow;

    // resident Q B-frags: col = query, k = cs*16 + hi*8 + j
    const int q = m0 + qh * 32 + col;
    f16x8 qf[4];
#pragma unroll
    for (int cs = 0; cs < 4; ++cs)
        qf[cs] = *reinterpret_cast<const f16x8*>(
            &Qb[(size_t)q * HC + cs * 16 + hi * 8]);

    const f32x16 Z16 = {0,0,0,0,0,0,0,0,0,0,0,0,0,0,0,0};
    f32x16 acc0 = Z16, acc1 = Z16;
    float m_run = -3.0e38f, l_run = 0.0f;

    const int kbase = sg * KSEG;

    // stage chunk [kc, kc+64) into buf: qh==0 wave stages K, qh==1 stages V.
    // Exactly 8 gload_lds per wave per call (the vmcnt accounting unit).
    auto stage = [&](int kc, int buf) {
        if (qh == 0) {
            const char* src = (const char*)(Kb + (size_t)kc * HC);
            char* dst = (char*)&SM[buf][sg][0][0];
#pragma unroll
            for (int g = 0; g < 8; ++g)
                gload_lds16(src + (size_t)(g * 8 + srow) * 128 + (sx << 4),
                            dst + g * 1024);
        } else {
            const char* src = (const char*)Vb + (size_t)kc * 2;
            char* dst = (char*)&SM[buf][sg][1][0];
#pragma unroll
            for (int g = 0; g < 8; ++g)
                gload_lds16(src + (size_t)(g * 8 + srow) * (NT * 2) + (sx << 4),
                            dst + g * 1024);
        }
    };

    // swizzled LDS read: 16B unit u of row stored at u ^ (row&7)
    auto rd = [&](const f16* base, int row, int u) -> f16x8 {
        return *reinterpret_cast<const f16x8*>(
            base + row * 64 + ((u ^ (row & 7)) << 3));
    };

    // prologue: 2-deep prefetch (16 outstanding vmem ops per wave)
    stage(kbase, 0);
    stage(kbase + 64, 1);

    for (int i = 0; i < NSEG; ++i) {
        const int cur = i & 1;

        // ---- counted wait: own chunk-i loads done (prefetch stays live) --
        if (i < NSEG - 1) asm volatile("s_waitcnt vmcnt(8)" ::: "memory");
        else              asm volatile("s_waitcnt vmcnt(0)" ::: "memory");
        SBAR();
        __builtin_amdgcn_s_barrier();   // all waves' chunk-i staging visible
        SBAR();

        const f16* Kc = &SM[cur][sg][0][0];
        const f16* Vc = &SM[cur][sg][1][0];

        // ---- QK^T: S[key][query]; A=K rows (key), B=Q -------------------
        f32x16 s0 = Z16, s1 = Z16;
        __builtin_amdgcn_s_setprio(1);
#pragma unroll
        for (int cs = 0; cs < 4; ++cs) {
            const f16x8 k0 = rd(Kc, col,      cs * 2 + hi);
            const f16x8 k1 = rd(Kc, 32 + col, cs * 2 + hi);
            s0 = MFMA32(k0, qf[cs], s0);
            s1 = MFMA32(k1, qf[cs], s1);
        }
        __builtin_amdgcn_s_setprio(0);

        // ---- softmax over this chunk (query = col), tree reductions -----
        float m8[8];
#pragma unroll
        for (int j = 0; j < 8; ++j)
            m8[j] = fmaxf(fmaxf(s0[2 * j], s0[2 * j + 1]),
                          fmaxf(s1[2 * j], s1[2 * j + 1]));
        float cm = fmaxf(fmaxf(fmaxf(m8[0], m8[1]), fmaxf(m8[2], m8[3])),
                         fmaxf(fmaxf(m8[4], m8[5]), fmaxf(m8[6], m8[7])));
        cm = fmaxf(cm, __shfl_xor(cm, 32));
        if (!__all(cm <= m_run + 8.0f)) {     // defer-max, THR=8
            const float mN = fmaxf(m_run, cm);
            const float fac = __expf(m_run - mN);
#pragma unroll
            for (int r = 0; r < 16; ++r) { acc0[r] *= fac; acc1[r] *= fac; }
            l_run *= fac;
            m_run = mN;
        }
        float p0[16], p1[16];
        float ps0 = 0.f, ps1 = 0.f, ps2 = 0.f, ps3 = 0.f;
#pragma unroll
        for (int r = 0; r < 4; ++r) {
            p0[r]      = __expf(s0[r]      - m_run); ps0 += p0[r];
            p0[r + 4]  = __expf(s0[r + 4]  - m_run); ps1 += p0[r + 4];
            p0[r + 8]  = __expf(s0[r + 8]  - m_run); ps2 += p0[r + 8];
            p0[r + 12] = __expf(s0[r + 12] - m_run); ps3 += p0[r + 12];
            p1[r]      = __expf(s1[r]      - m_run); ps0 += p1[r];
            p1[r + 4]  = __expf(s1[r + 4]  - m_run); ps1 += p1[r + 4];
            p1[r + 8]  = __expf(s1[r + 8]  - m_run); ps2 += p1[r + 8];
            p1[r + 12] = __expf(s1[r + 12] - m_run); ps3 += p1[r + 12];
        }
        l_run += (ps0 + ps1) + (ps2 + ps3);

        // ---- P -> f16 B-frags in-register (pkrtz + permlane32_swap) -----
        unsigned a0[8], a1[8];
#pragma unroll
        for (int j = 0; j < 8; ++j) {
            a0[j] = pkh(p0[2 * j], p0[2 * j + 1]);
            a1[j] = pkh(p1[2 * j], p1[2 * j + 1]);
        }
        swap32(a0[0], a0[2]); swap32(a0[1], a0[3]);   // keys 0-15
        swap32(a0[4], a0[6]); swap32(a0[5], a0[7]);   // keys 16-31
        swap32(a1[0], a1[2]); swap32(a1[1], a1[3]);   // keys 32-47
        swap32(a1[4], a1[6]); swap32(a1[5], a1[7]);   // keys 48-63
        union BU { unsigned u[4]; f16x8 v; };
        BU fr[4];
        fr[0].u[0] = a0[0]; fr[0].u[1] = a0[1]; fr[0].u[2] = a0[2]; fr[0].u[3] = a0[3];
        fr[1].u[0] = a0[4]; fr[1].u[1] = a0[5]; fr[1].u[2] = a0[6]; fr[1].u[3] = a0[7];
        fr[2].u[0] = a1[0]; fr[2].u[1] = a1[1]; fr[2].u[2] = a1[2]; fr[2].u[3] = a1[3];
        fr[3].u[0] = a1[4]; fr[3].u[1] = a1[5]; fr[3].u[2] = a1[6]; fr[3].u[3] = a1[7];

        // ---- O += V @ P: A=V rows (channel), B=P ------------------------
        __builtin_amdgcn_s_setprio(1);
#pragma unroll
        for (int kk = 0; kk < 4; ++kk) {
            const f16x8 v0 = rd(Vc, col,      kk * 2 + hi);
            const f16x8 v1 = rd(Vc, 32 + col, kk * 2 + hi);
            acc0 = MFMA32(v0, fr[kk].v, acc0);
            acc1 = MFMA32(v1, fr[kk].v, acc1);
        }
        __builtin_amdgcn_s_setprio(0);

        // ---- all waves done reading buf[cur]; refill it 2 chunks ahead --
        SBAR();
        __builtin_amdgcn_s_barrier();
        SBAR();
        if (i + 2 < NSEG) stage(kbase + (i + 2) * 64, cur);
    }

    // ---- publish segment partials (reuse SM as f32 Part[2][64][64]) -----
    float* Part = (float*)&SM[0][0][0][0];
    const float l_full = l_run + __shfl_xor(l_run, 32);
    if (hi == 0) {
        Ml[sg][qh * 32 + col] = m_run;
        Ll[sg][qh * 32 + col] = l_full;
    }
    {
        float* row = Part + ((size_t)sg * 64 + qh * 32 + col) * 64;
#pragma unroll
        for (int rq = 0; rq < 4; ++rq) {
            const int c0 = rq * 8 + hi * 4;
            f32x4 o0 = {acc0[rq * 4 + 0], acc0[rq * 4 + 1],
                        acc0[rq * 4 + 2], acc0[rq * 4 + 3]};
            f32x4 o1 = {acc1[rq * 4 + 0], acc1[rq * 4 + 1],
                        acc1[rq * 4 + 2], acc1[rq * 4 + 3]};
            *reinterpret_cast<f32x4*>(row + c0) = o0;
            *reinterpret_cast<f32x4*>(row + 32 + c0) = o1;
        }
    }
    __syncthreads();

    // ---- merge the two segments; thread t: (q = t>>2, c = (t&3)*16..) ---
    {
        const int qq = t >> 2, c0 = (t & 3) * 16;
        const float mA = Ml[0][qq], mB = Ml[1][qq];
        const float M = fmaxf(mA, mB);
        const float wA = __expf(mA - M), wB = __expf(mB - M);
        const float inv = 1.0f / (wA * Ll[0][qq] + wB * Ll[1][qq]);
        const float* r0 = Part + (size_t)qq * 64;
        const float* r1 = Part + (size_t)(64 + qq) * 64;
        f16* dst = &Ot[((size_t)(b * NT + m0 + qq)) * CH + h * HC + c0];
#pragma unroll
        for (int j = 0; j < 16; j += 4) {
            const f32x4 aA = *reinterpret_cast<const f32x4*>(r0 + c0 + j);
            const f32x4 aB = *reinterpret_cast<const f32x4*>(r1 + c0 + j);
            f16x4 o = {(f16)((wA * aA[0] + wB * aB[0]) * inv),
                       (f16)((wA * aA[1] + wB * aB[1]) * inv),
                       (f16)((wA * aA[2] + wB * aB[2]) * inv),
                       (f16)((wA * aA[3] + wB * aB[3]) * inv)};
            *reinterpret_cast<f16x4*>(dst + j) = o;
        }
    }
}

// ---------------------------------------------------------------------------
// Final conv1x1 (unchanged). grid (36, 4, 4).
// ---------------------------------------------------------------------------
__global__ __launch_bounds__(256) void out_gemm_mfma(
    const float* __restrict__ wo, const float* __restrict__ bo,
    const f16* __restrict__ Ot, float* __restrict__ Y)
{
    const int t = threadIdx.x, l = t & 63, w = t >> 6;
    const int lm = l & 15, lg = l >> 4;
    const int n0 = blockIdx.x * 64;
    const int o0 = blockIdx.y * 64;
    const int b = blockIdx.z;

    f32x4 acc[4] = {{0.f,0.f,0.f,0.f},{0.f,0.f,0.f,0.f},
                    {0.f,0.f,0.f,0.f},{0.f,0.f,0.f,0.f}};
    const int o_row = o0 + w * 16 + lm;

#pragma unroll
    for (int ks = 0; ks < 8; ++ks) {
        const float* wp = &wo[(size_t)o_row * CH + ks * 32 + lg * 8];
        const float4 wa = *reinterpret_cast<const float4*>(wp);
        const float4 wb = *reinterpret_cast<const float4*>(wp + 4);
        const f16x8 a = {(f16)wa.x, (f16)wa.y, (f16)wa.z, (f16)wa.w,
                         (f16)wb.x, (f16)wb.y, (f16)wb.z, (f16)wb.w};
#pragma unroll
        for (int nt = 0; nt < 4; ++nt) {
            const f16x8 bf = *reinterpret_cast<const f16x8*>(
                &Ot[((size_t)(b * NT + n0 + nt * 16 + lm)) * CH + ks * 32 + lg * 8]);
            acc[nt] = MFMA16(a, bf, acc[nt]);
        }
    }

    const int ob = o0 + w * 16 + lg * 4;
    const float4 bias4 = *reinterpret_cast<const float4*>(&bo[ob]);
    const float bb[4] = {bias4.x, bias4.y, bias4.z, bias4.w};
#pragma unroll
    for (int nt = 0; nt < 4; ++nt) {
        const int n = n0 + nt * 16 + lm;
#pragma unroll
        for (int r = 0; r < 4; ++r)
            Y[((size_t)(b * CH + ob + r)) * NT + n] = acc[nt][r] + bb[r];
    }
}

// ---------------------------------------------------------------------------
extern "C" void kernel_launch(void* const* d_in, const int* in_sizes, int n_in,
                              void* d_out, int out_size, void* d_ws, size_t ws_size,
                              hipStream_t stream) {
    (void)in_sizes; (void)n_in; (void)out_size; (void)ws_size;
    const float* x  = (const float*)d_in[0];
    const float* wk = (const float*)d_in[1];
    const float* bk = (const float*)d_in[2];
    const float* wq = (const float*)d_in[3];
    const float* bq = (const float*)d_in[4];
    const float* wv = (const float*)d_in[5];
    const float* bv = (const float*)d_in[6];
    const float* wo = (const float*)d_in[7];
    const float* bo = (const float*)d_in[8];
    float* out = (float*)d_out;

    const size_t SZ = (size_t)NB * NT * CH;   // halves per tensor
    f16* Kt = (f16*)d_ws;        // [b][h][n][c]
    f16* Qt = Kt + SZ;           // [b][h][n][c]
    f16* Vg = Qt + SZ;           // [b][h][c][n]
    f16* Ot = Vg + SZ;           // [b][n][c]

    proj_qkv_mfma<<<dim3(36, 3, 4), 256, 0, stream>>>(
        wk, bk, wq, bq, wv, bv, x, Kt, Qt, Vg);
    attn_pipe<<<dim3(576), 256, 0, stream>>>(Kt, Qt, Vg, Ot);
    out_gemm_mfma<<<dim3(36, 4, 4), 256, 0, stream>>>(wo, bo, Ot, out);
}

// Round 11
// 109.759 us; speedup vs baseline: 1.0197x; 1.0197x over previous
//
#include <hip/hip_runtime.h>
#include <math.h>

#define NB 4
#define CH 256
#define NHEADS 4
#define HC 64
#define NT 2304    // 48*48
#define KSEG 576   // keys per segment (split-K x4)
#define NSEG 9     // 64-key chunks per segment

typedef _Float16 f16;
typedef _Float16 f16x4 __attribute__((ext_vector_type(4)));
typedef _Float16 f16x8 __attribute__((ext_vector_type(8)));
typedef float f32x4 __attribute__((ext_vector_type(4)));
typedef float f32x16 __attribute__((ext_vector_type(16)));

#define MFMA16(a, b, c) __builtin_amdgcn_mfma_f32_16x16x32_f16(a, b, c, 0, 0, 0)
#define MFMA32(a, b, c) __builtin_amdgcn_mfma_f32_32x32x16_f16(a, b, c, 0, 0, 0)

__device__ __forceinline__ void gload_lds16(const void* g, void* l) {
    __builtin_amdgcn_global_load_lds(
        (const __attribute__((address_space(1))) unsigned int*)g,
        (__attribute__((address_space(3))) unsigned int*)l, 16, 0, 0);
}

__device__ __forceinline__ unsigned pkh(float a, float b) {
    auto r = __builtin_amdgcn_cvt_pkrtz(a, b);   // __fp16 ext_vector(2)
    return __builtin_bit_cast(unsigned, r);
}
// v_permlane32_swap_b32: new_a = [a.lo32 | b.lo32_old], new_b = [a.hi32_old | b.hi32]
__device__ __forceinline__ void swap32(unsigned& a, unsigned& b) {
    asm volatile("v_permlane32_swap_b32 %0, %1" : "+v"(a), "+v"(b));
}

// ---------------------------------------------------------------------------
// Fused K/Q/V projection reading x directly (unchanged from R9/R10).
// grid (36, 3, 4), block 256. Outputs: K,Q [b][h][n][64c]; V [b][h][64c][n].
// ---------------------------------------------------------------------------
__global__ __launch_bounds__(256) void proj_qkv_mfma(
    const float* __restrict__ wk, const float* __restrict__ bk,
    const float* __restrict__ wq, const float* __restrict__ bq,
    const float* __restrict__ wv, const float* __restrict__ bv,
    const float* __restrict__ X,
    f16* __restrict__ Kt, f16* __restrict__ Qt, f16* __restrict__ Vg)
{
    const int t = threadIdx.x, l = t & 63, w = t >> 6;
    const int lm = l & 15, lg = l >> 4;
    const int n0 = blockIdx.x * 64;
    const int sel = blockIdx.y;
    const int b = blockIdx.z;

    const float* W  = sel == 0 ? wk : (sel == 1 ? wq : wv);
    const float* Bi = sel == 0 ? bk : (sel == 1 ? bq : bv);

    f32x4 acc[4][4] = {};   // [h][nt]

#pragma unroll 2
    for (int ks = 0; ks < 8; ++ks) {
        f16x8 bf[4];
#pragma unroll
        for (int nt = 0; nt < 4; ++nt) {
            const float* xp = &X[((size_t)b * CH + ks * 32 + lg * 8) * NT
                                 + n0 + nt * 16 + lm];
            f16x8 v;
#pragma unroll
            for (int j = 0; j < 8; ++j) v[j] = (f16)xp[(size_t)j * NT];
            bf[nt] = v;
        }
#pragma unroll
        for (int h = 0; h < 4; ++h) {
            const float* wp = &W[(size_t)(h * 64 + w * 16 + lm) * CH + ks * 32 + lg * 8];
            const float4 wa = *reinterpret_cast<const float4*>(wp);
            const float4 wb = *reinterpret_cast<const float4*>(wp + 4);
            const f16x8 a = {(f16)wa.x, (f16)wa.y, (f16)wa.z, (f16)wa.w,
                             (f16)wb.x, (f16)wb.y, (f16)wb.z, (f16)wb.w};
#pragma unroll
            for (int nt = 0; nt < 4; ++nt)
                acc[h][nt] = MFMA16(a, bf[nt], acc[h][nt]);
        }
    }

    const int c_base = w * 16 + lg * 4;
#pragma unroll
    for (int h = 0; h < 4; ++h) {
        const float4 b4 = *reinterpret_cast<const float4*>(&Bi[h * 64 + c_base]);
        const float bb[4] = {b4.x, b4.y, b4.z, b4.w};
        if (sel < 2) {
            f16* Out = sel == 0 ? Kt : Qt;
#pragma unroll
            for (int nt = 0; nt < 4; ++nt) {
                const int n = n0 + nt * 16 + lm;
                f16x4 o = {(f16)(acc[h][nt][0] + bb[0]), (f16)(acc[h][nt][1] + bb[1]),
                           (f16)(acc[h][nt][2] + bb[2]), (f16)(acc[h][nt][3] + bb[3])};
                *reinterpret_cast<f16x4*>(
                    &Out[((size_t)((b * NHEADS + h) * NT + n)) * HC + c_base]) = o;
            }
        } else {
#pragma unroll
            for (int nt = 0; nt < 4; ++nt) {
                const int n = n0 + nt * 16 + lm;
#pragma unroll
                for (int r = 0; r < 4; ++r)
                    Vg[((size_t)((b * NHEADS + h) * HC + c_base + r)) * NT + n] =
                        (f16)(acc[h][nt][r] + bb[r]);
            }
        }
    }
}

// ---------------------------------------------------------------------------
// Flash attention, 32x32x16 MFMA, SPLIT-K x4, 8-wave blocks (512 thr).
// Wave = (qh in 0,1) x (seg in 0..3); segment = 576 keys = 9 chunks of 64.
// Offered parallelism 4608 waves -> 16 waves/CU (2 blocks x 8 waves; VGPR-
// and LDS-capped at exactly 2 blocks/CU). R9's proven single-buffer barrier
// structure, swizzled gload_lds staging, in-register P (pkrtz+permlane),
// defer-max THR=8. Exact 4-way f32 merge of segment partials at the end.
// XCD decode: xcd = bid&7 owns 2 (b,h) pairs -> L2-resident K/V.
// grid 576, block 512.
// ---------------------------------------------------------------------------
__global__ __launch_bounds__(512, 4) void attn_split4(
    const f16* __restrict__ Kt, const f16* __restrict__ Qt,
    const f16* __restrict__ Vg, f16* __restrict__ Ot)
{
    __shared__ f16 SM[4][2][4096];   // [seg][K/V][64 rows x 64c] = 64KB
    __shared__ float Ml[4][64], Ll[4][64];

    const int t = threadIdx.x, l = t & 63, w = t >> 6;
    const int col = l & 31, hi = l >> 5;
    const int qh = w & 1, sg = w >> 1;   // query half (0..1), key segment (0..3)

    const int bid = blockIdx.x;
    const int xcd = bid & 7, idx = bid >> 3;
    const int bh  = 2 * xcd + (idx >= 36 ? 1 : 0);
    const int qt  = idx >= 36 ? idx - 36 : idx;
    const int b = bh >> 2, h = bh & 3;
    const int m0 = qt * 64;

    const size_t bhs = (size_t)(b * NHEADS + h);
    const f16* Kb = Kt + bhs * NT * HC;   // [n][64c] rows of 128 B
    const f16* Qb = Qt + bhs * NT * HC;
    const f16* Vb = Vg + bhs * HC * NT;   // [c][n]

    const int srow = l >> 3, su = l & 7, sx = su ^ srow;

    // resident Q B-frags: col = query, k = cs*16 + hi*8 + j
    const int q = m0 + qh * 32 + col;
    f16x8 qf[4];
#pragma unroll
    for (int cs = 0; cs < 4; ++cs)
        qf[cs] = *reinterpret_cast<const f16x8*>(
            &Qb[(size_t)q * HC + cs * 16 + hi * 8]);

    const f32x16 Z16 = {0,0,0,0,0,0,0,0,0,0,0,0,0,0,0,0};
    f32x16 acc0 = Z16, acc1 = Z16;
    float m_run = -3.0e38f, l_run = 0.0f;

    const int kbase = sg * KSEG;

    // stage chunk [kc, kc+64) of segment sg: qh==0 stages K, qh==1 stages V.
    auto stage = [&](int kc) {
        if (qh == 0) {
            const char* src = (const char*)(Kb + (size_t)kc * HC);
            char* dst = (char*)&SM[sg][0][0];
#pragma unroll
            for (int g = 0; g < 8; ++g)
                gload_lds16(src + (size_t)(g * 8 + srow) * 128 + (sx << 4),
                            dst + g * 1024);
        } else {
            const char* src = (const char*)Vb + (size_t)kc * 2;
            char* dst = (char*)&SM[sg][1][0];
#pragma unroll
            for (int g = 0; g < 8; ++g)
                gload_lds16(src + (size_t)(g * 8 + srow) * (NT * 2) + (sx << 4),
                            dst + g * 1024);
        }
    };

    // swizzled LDS read: 16B unit u of row stored at u ^ (row&7)
    auto rd = [&](const f16* base, int row, int u) -> f16x8 {
        return *reinterpret_cast<const f16x8*>(
            base + row * 64 + ((u ^ (row & 7)) << 3));
    };

    stage(kbase);
    __syncthreads();

    for (int i = 0; i < NSEG; ++i) {
        const f16* Kc = &SM[sg][0][0];
        const f16* Vc = &SM[sg][1][0];

        // ---- QK^T: S[key][query]; A=K rows (key), B=Q -------------------
        f32x16 s0 = Z16, s1 = Z16;
#pragma unroll
        for (int cs = 0; cs < 4; ++cs) {
            const f16x8 k0 = rd(Kc, col,      cs * 2 + hi);
            const f16x8 k1 = rd(Kc, 32 + col, cs * 2 + hi);
            s0 = MFMA32(k0, qf[cs], s0);
            s1 = MFMA32(k1, qf[cs], s1);
        }

        // ---- softmax over this chunk (query = col), tree reductions -----
        float m8[8];
#pragma unroll
        for (int j = 0; j < 8; ++j)
            m8[j] = fmaxf(fmaxf(s0[2 * j], s0[2 * j + 1]),
                          fmaxf(s1[2 * j], s1[2 * j + 1]));
        float cm = fmaxf(fmaxf(fmaxf(m8[0], m8[1]), fmaxf(m8[2], m8[3])),
                         fmaxf(fmaxf(m8[4], m8[5]), fmaxf(m8[6], m8[7])));
        cm = fmaxf(cm, __shfl_xor(cm, 32));
        if (!__all(cm <= m_run + 8.0f)) {     // defer-max, THR=8
            const float mN = fmaxf(m_run, cm);
            const float fac = __expf(m_run - mN);
#pragma unroll
            for (int r = 0; r < 16; ++r) { acc0[r] *= fac; acc1[r] *= fac; }
            l_run *= fac;
            m_run = mN;
        }
        float p0[16], p1[16];
        float ps0 = 0.f, ps1 = 0.f, ps2 = 0.f, ps3 = 0.f;
#pragma unroll
        for (int r = 0; r < 4; ++r) {
            p0[r]      = __expf(s0[r]      - m_run); ps0 += p0[r];
            p0[r + 4]  = __expf(s0[r + 4]  - m_run); ps1 += p0[r + 4];
            p0[r + 8]  = __expf(s0[r + 8]  - m_run); ps2 += p0[r + 8];
            p0[r + 12] = __expf(s0[r + 12] - m_run); ps3 += p0[r + 12];
            p1[r]      = __expf(s1[r]      - m_run); ps0 += p1[r];
            p1[r + 4]  = __expf(s1[r + 4]  - m_run); ps1 += p1[r + 4];
            p1[r + 8]  = __expf(s1[r + 8]  - m_run); ps2 += p1[r + 8];
            p1[r + 12] = __expf(s1[r + 12] - m_run); ps3 += p1[r + 12];
        }
        l_run += (ps0 + ps1) + (ps2 + ps3);

        // ---- P -> f16 B-frags in-register (pkrtz + permlane32_swap) -----
        unsigned a0[8], a1[8];
#pragma unroll
        for (int j = 0; j < 8; ++j) {
            a0[j] = pkh(p0[2 * j], p0[2 * j + 1]);
            a1[j] = pkh(p1[2 * j], p1[2 * j + 1]);
        }
        swap32(a0[0], a0[2]); swap32(a0[1], a0[3]);   // keys 0-15
        swap32(a0[4], a0[6]); swap32(a0[5], a0[7]);   // keys 16-31
        swap32(a1[0], a1[2]); swap32(a1[1], a1[3]);   // keys 32-47
        swap32(a1[4], a1[6]); swap32(a1[5], a1[7]);   // keys 48-63
        union BU { unsigned u[4]; f16x8 v; };
        BU fr[4];
        fr[0].u[0] = a0[0]; fr[0].u[1] = a0[1]; fr[0].u[2] = a0[2]; fr[0].u[3] = a0[3];
        fr[1].u[0] = a0[4]; fr[1].u[1] = a0[5]; fr[1].u[2] = a0[6]; fr[1].u[3] = a0[7];
        fr[2].u[0] = a1[0]; fr[2].u[1] = a1[1]; fr[2].u[2] = a1[2]; fr[2].u[3] = a1[3];
        fr[3].u[0] = a1[4]; fr[3].u[1] = a1[5]; fr[3].u[2] = a1[6]; fr[3].u[3] = a1[7];

        // ---- O += V @ P: A=V rows (channel), B=P ------------------------
#pragma unroll
        for (int kk = 0; kk < 4; ++kk) {
            const f16x8 v0 = rd(Vc, col,      kk * 2 + hi);
            const f16x8 v1 = rd(Vc, 32 + col, kk * 2 + hi);
            acc0 = MFMA32(v0, fr[kk].v, acc0);
            acc1 = MFMA32(v1, fr[kk].v, acc1);
        }

        __syncthreads();                       // all waves done with buffer
        if (i + 1 < NSEG) {
            stage(kbase + (i + 1) * 64);       // overwrite with next chunk
            __syncthreads();                   // staged (vmcnt drained)
        }
    }

    // ---- publish segment partials (reuse SM as f32 Part[4*64][64]) ------
    float* Part = (float*)&SM[0][0][0];
    const float l_full = l_run + __shfl_xor(l_run, 32);
    __syncthreads();   // compute done everywhere before overwriting SM
    if (hi == 0) {
        Ml[sg][qh * 32 + col] = m_run;
        Ll[sg][qh * 32 + col] = l_full;
    }
    {
        float* row = Part + ((size_t)(sg * 64 + qh * 32 + col)) * 64;
#pragma unroll
        for (int rq = 0; rq < 4; ++rq) {
            const int c0 = rq * 8 + hi * 4;
            f32x4 o0 = {acc0[rq * 4 + 0], acc0[rq * 4 + 1],
                        acc0[rq * 4 + 2], acc0[rq * 4 + 3]};
            f32x4 o1 = {acc1[rq * 4 + 0], acc1[rq * 4 + 1],
                        acc1[rq * 4 + 2], acc1[rq * 4 + 3]};
            *reinterpret_cast<f32x4*>(row + c0) = o0;
            *reinterpret_cast<f32x4*>(row + 32 + c0) = o1;
        }
    }
    __syncthreads();

    // ---- 4-way merge; thread t: (q = t>>3, channels c0 = (t&7)*8) -------
    {
        const int qq = t >> 3, c0 = (t & 7) * 8;
        const float m0_ = Ml[0][qq], m1_ = Ml[1][qq];
        const float m2_ = Ml[2][qq], m3_ = Ml[3][qq];
        const float M = fmaxf(fmaxf(m0_, m1_), fmaxf(m2_, m3_));
        const float w0 = __expf(m0_ - M), w1 = __expf(m1_ - M);
        const float w2 = __expf(m2_ - M), w3 = __expf(m3_ - M);
        const float inv = 1.0f / (w0 * Ll[0][qq] + w1 * Ll[1][qq]
                                + w2 * Ll[2][qq] + w3 * Ll[3][qq]);
        const float* r0 = Part + (size_t)(0 * 64 + qq) * 64 + c0;
        const float* r1 = Part + (size_t)(1 * 64 + qq) * 64 + c0;
        const float* r2 = Part + (size_t)(2 * 64 + qq) * 64 + c0;
        const float* r3 = Part + (size_t)(3 * 64 + qq) * 64 + c0;
        f16x8 o;
#pragma unroll
        for (int j = 0; j < 8; ++j)
            o[j] = (f16)((w0 * r0[j] + w1 * r1[j] + w2 * r2[j] + w3 * r3[j]) * inv);
        *reinterpret_cast<f16x8*>(
            &Ot[((size_t)(b * NT + m0 + qq)) * CH + h * HC + c0]) = o;
    }
}

// ---------------------------------------------------------------------------
// Final conv1x1 (unchanged). grid (36, 4, 4).
// ---------------------------------------------------------------------------
__global__ __launch_bounds__(256) void out_gemm_mfma(
    const float* __restrict__ wo, const float* __restrict__ bo,
    const f16* __restrict__ Ot, float* __restrict__ Y)
{
    const int t = threadIdx.x, l = t & 63, w = t >> 6;
    const int lm = l & 15, lg = l >> 4;
    const int n0 = blockIdx.x * 64;
    const int o0 = blockIdx.y * 64;
    const int b = blockIdx.z;

    f32x4 acc[4] = {{0.f,0.f,0.f,0.f},{0.f,0.f,0.f,0.f},
                    {0.f,0.f,0.f,0.f},{0.f,0.f,0.f,0.f}};
    const int o_row = o0 + w * 16 + lm;

#pragma unroll
    for (int ks = 0; ks < 8; ++ks) {
        const float* wp = &wo[(size_t)o_row * CH + ks * 32 + lg * 8];
        const float4 wa = *reinterpret_cast<const float4*>(wp);
        const float4 wb = *reinterpret_cast<const float4*>(wp + 4);
        const f16x8 a = {(f16)wa.x, (f16)wa.y, (f16)wa.z, (f16)wa.w,
                         (f16)wb.x, (f16)wb.y, (f16)wb.z, (f16)wb.w};
#pragma unroll
        for (int nt = 0; nt < 4; ++nt) {
            const f16x8 bf = *reinterpret_cast<const f16x8*>(
                &Ot[((size_t)(b * NT + n0 + nt * 16 + lm)) * CH + ks * 32 + lg * 8]);
            acc[nt] = MFMA16(a, bf, acc[nt]);
        }
    }

    const int ob = o0 + w * 16 + lg * 4;
    const float4 bias4 = *reinterpret_cast<const float4*>(&bo[ob]);
    const float bb[4] = {bias4.x, bias4.y, bias4.z, bias4.w};
#pragma unroll
    for (int nt = 0; nt < 4; ++nt) {
        const int n = n0 + nt * 16 + lm;
#pragma unroll
        for (int r = 0; r < 4; ++r)
            Y[((size_t)(b * CH + ob + r)) * NT + n] = acc[nt][r] + bb[r];
    }
}

// ---------------------------------------------------------------------------
extern "C" void kernel_launch(void* const* d_in, const int* in_sizes, int n_in,
                              void* d_out, int out_size, void* d_ws, size_t ws_size,
                              hipStream_t stream) {
    (void)in_sizes; (void)n_in; (void)out_size; (void)ws_size;
    const float* x  = (const float*)d_in[0];
    const float* wk = (const float*)d_in[1];
    const float* bk = (const float*)d_in[2];
    const float* wq = (const float*)d_in[3];
    const float* bq = (const float*)d_in[4];
    const float* wv = (const float*)d_in[5];
    const float* bv = (const float*)d_in[6];
    const float* wo = (const float*)d_in[7];
    const float* bo = (const float*)d_in[8];
    float* out = (float*)d_out;

    const size_t SZ = (size_t)NB * NT * CH;   // halves per tensor
    f16* Kt = (f16*)d_ws;        // [b][h][n][c]
    f16* Qt = Kt + SZ;           // [b][h][n][c]
    f16* Vg = Qt + SZ;           // [b][h][c][n]
    f16* Ot = Vg + SZ;           // [b][n][c]

    proj_qkv_mfma<<<dim3(36, 3, 4), 256, 0, stream>>>(
        wk, bk, wq, bq, wv, bv, x, Kt, Qt, Vg);
    attn_split4<<<dim3(576), 512, 0, stream>>>(Kt, Qt, Vg, Ot);
    out_gemm_mfma<<<dim3(36, 4, 4), 256, 0, stream>>>(wo, bo, Ot, out);
}